// Round 1
// baseline (4119.506 us; speedup 1.0000x reference)
//
#include <hip/hip_runtime.h>

#define SEQ_T 2048
#define BATCH 64

typedef _Float16 half2v __attribute__((ext_vector_type(2)));

#if defined(__has_builtin)
#  if __has_builtin(__builtin_amdgcn_fdot2)
#    define HAVE_FDOT2 1
#  endif
#endif

__device__ __forceinline__ float fdot2f(half2v a, half2v b, float c) {
#ifdef HAVE_FDOT2
  return __builtin_amdgcn_fdot2(a, b, c, false);
#else
  return c + (float)a[0] * (float)b[0] + (float)a[1] * (float)b[1];
#endif
}

__device__ __forceinline__ float sigmoid_fast(float x) {
  return 1.f / (1.f + __expf(-x));
}
__device__ __forceinline__ float tanh_fast(float x) {
  // 1 - 2/(1+exp(2x)); correct saturation at +/-inf
  return 1.f - 2.f / (1.f + __expf(2.f * x));
}

// One workgroup per batch element. 512 threads = 512 gate rows (torch order i,f,g,o).
// Weights live in VGPRs as f16 pairs; h lives in LDS as f16; c in f32 regs of threads 0..127.
// x_t staged through a 2-slot LDS ring by wave-2 lanes 0..31 (issue loads early, ds_write late).
template <int K_IN, bool IN_F32, bool WRITE_H16, bool WRITE_OUT>
__global__ __launch_bounds__(512, 2) void lstm_rec(
    const float* __restrict__ Wih, const float* __restrict__ Whh,
    const float* __restrict__ bih, const float* __restrict__ bhh,
    const void* __restrict__ xin,            // [T][B][K_IN] f32 (layer0) or f16 (layer1)
    unsigned short* __restrict__ hout,       // [T][B][128] f16 (layer0 only)
    const float* __restrict__ wlin, const float* __restrict__ blin,
    float* __restrict__ out)                 // [T][B] (layer1 only)
{
  constexpr int H = 128;
  constexpr int G = 512;
  constexpr int KP_IN = K_IN / 2;   // input f16 pairs per gate row
  constexpr int E = K_IN / 32;      // x elements per loader lane (32 lanes)

  const int b = blockIdx.x;
  const int r = threadIdx.x;        // gate row

  __shared__ __align__(16) _Float16 xring[2][K_IN];
  __shared__ __align__(16) _Float16 hbuf[H];
  __shared__ float gates[G];
  __shared__ float redpart[2];

  // ---- stage weights into registers as f16 pairs (one-time) ----
  half2v wx[KP_IN];
  half2v wh[H / 2];
  {
    const float2* p = reinterpret_cast<const float2*>(Wih + (size_t)r * K_IN);
#pragma unroll
    for (int k = 0; k < KP_IN; k++) {
      float2 f = p[k];
      half2v v; v[0] = (_Float16)f.x; v[1] = (_Float16)f.y;
      wx[k] = v;
    }
    const float2* q = reinterpret_cast<const float2*>(Whh + (size_t)r * H);
#pragma unroll
    for (int k = 0; k < H / 2; k++) {
      float2 f = q[k];
      half2v v; v[0] = (_Float16)f.x; v[1] = (_Float16)f.y;
      wh[k] = v;
    }
  }
  const float bias = bih[r] + bhh[r];
  float c = 0.f;
  float wl = 0.f, bl = 0.f;
  if constexpr (WRITE_OUT) {
    if (r < H) wl = wlin[r];
    bl = blin[0];
  }

  if (r < H) hbuf[r] = (_Float16)0.f;

  const bool loader = (r >= 128) && (r < 160);  // wave 2, lanes 0..31
  const int l = r - 128;

  // prologue: x(0) -> ring slot 0
  if (loader) {
    const size_t base = (size_t)b * K_IN + (size_t)l * E;
    if constexpr (IN_F32) {
      const float2 f = *reinterpret_cast<const float2*>((const float*)xin + base);
      half2v v; v[0] = (_Float16)f.x; v[1] = (_Float16)f.y;
      *reinterpret_cast<unsigned int*>(&xring[0][l * E]) = __builtin_bit_cast(unsigned int, v);
    } else {
      const uint2 u = *reinterpret_cast<const uint2*>((const unsigned short*)xin + base);
      *reinterpret_cast<uint2*>(&xring[0][l * E]) = u;
    }
  }
  __syncthreads();

  for (int t = 0; t < SEQ_T; ++t) {
    const int cur = t & 1, nxt = cur ^ 1;

    // issue x(t+1) loads early; latency hides under the dot phase
    float2 lf; uint2 lu;
    if (loader) {
      const int tn = (t + 1 < SEQ_T) ? (t + 1) : t;
      const size_t base = ((size_t)tn * BATCH + b) * K_IN + (size_t)l * E;
      if constexpr (IN_F32) lf = *reinterpret_cast<const float2*>((const float*)xin + base);
      else                  lu = *reinterpret_cast<const uint2*>((const unsigned short*)xin + base);
    }

    // ---- gate pre-activation: bias + Wih.x_t + Whh.h ----
    float a0 = bias, a1 = 0.f, a2 = 0.f, a3 = 0.f;
    {
      const uint4* xv = reinterpret_cast<const uint4*>(&xring[cur][0]);
#pragma unroll
      for (int i = 0; i < KP_IN / 4; i++) {
        const uint4 u = xv[i];
        a0 = fdot2f(wx[4 * i + 0], __builtin_bit_cast(half2v, u.x), a0);
        a1 = fdot2f(wx[4 * i + 1], __builtin_bit_cast(half2v, u.y), a1);
        a2 = fdot2f(wx[4 * i + 2], __builtin_bit_cast(half2v, u.z), a2);
        a3 = fdot2f(wx[4 * i + 3], __builtin_bit_cast(half2v, u.w), a3);
      }
      const uint4* hv = reinterpret_cast<const uint4*>(&hbuf[0]);
#pragma unroll
      for (int i = 0; i < H / 8; i++) {
        const uint4 u = hv[i];
        a0 = fdot2f(wh[4 * i + 0], __builtin_bit_cast(half2v, u.x), a0);
        a1 = fdot2f(wh[4 * i + 1], __builtin_bit_cast(half2v, u.y), a1);
        a2 = fdot2f(wh[4 * i + 2], __builtin_bit_cast(half2v, u.z), a2);
        a3 = fdot2f(wh[4 * i + 3], __builtin_bit_cast(half2v, u.w), a3);
      }
    }
    const float g = (a0 + a1) + (a2 + a3);
    // rows [0,256): i,f -> sigmoid; [256,384): g -> tanh; [384,512): o -> sigmoid
    const float act = (r >= 256 && r < 384) ? tanh_fast(g) : sigmoid_fast(g);
    gates[r] = act;
    __syncthreads();

    // ---- cell/hidden update (threads 0..127) ; ring write (loader lanes) ----
    if (r < H) {
      const float gi = gates[r];
      const float gf = gates[H + r];
      const float gg = gates[2 * H + r];
      const float go = gates[3 * H + r];
      c = gf * c + gi * gg;
      const float h = go * tanh_fast(c);
      hbuf[r] = (_Float16)h;
      if constexpr (WRITE_H16) {
        hout[((size_t)t * BATCH + b) * H + r] =
            __builtin_bit_cast(unsigned short, (_Float16)h);
      }
      if constexpr (WRITE_OUT) {
        float p = h * wl;
#pragma unroll
        for (int off = 32; off; off >>= 1) p += __shfl_xor(p, off);
        if ((r & 63) == 0) redpart[r >> 6] = p;
      }
    } else if (loader) {
      if constexpr (IN_F32) {
        half2v v; v[0] = (_Float16)lf.x; v[1] = (_Float16)lf.y;
        *reinterpret_cast<unsigned int*>(&xring[nxt][l * E]) = __builtin_bit_cast(unsigned int, v);
      } else {
        *reinterpret_cast<uint2*>(&xring[nxt][l * E]) = lu;
      }
    }
    __syncthreads();

    if constexpr (WRITE_OUT) {
      if (r == 0) out[(size_t)t * BATCH + b] = redpart[0] + redpart[1] + bl;
    }
  }
}

extern "C" void kernel_launch(void* const* d_in, const int* in_sizes, int n_in,
                              void* d_out, int out_size, void* d_ws, size_t ws_size,
                              hipStream_t stream) {
  (void)in_sizes; (void)n_in; (void)out_size; (void)ws_size;

  const float* data = (const float*)d_in[0];
  const float* Wih0 = (const float*)d_in[1];
  const float* Whh0 = (const float*)d_in[2];
  const float* bih0 = (const float*)d_in[3];
  const float* bhh0 = (const float*)d_in[4];
  const float* Wih1 = (const float*)d_in[5];
  const float* Whh1 = (const float*)d_in[6];
  const float* bih1 = (const float*)d_in[7];
  const float* bhh1 = (const float*)d_in[8];
  const float* Wlin = (const float*)d_in[9];
  const float* blin = (const float*)d_in[10];

  // ws: h0_all [2048][64][128] f16 = 32 MiB
  unsigned short* h0 = (unsigned short*)d_ws;

  lstm_rec<64, true, true, false><<<dim3(BATCH), dim3(512), 0, stream>>>(
      Wih0, Whh0, bih0, bhh0, data, h0, nullptr, nullptr, nullptr);

  lstm_rec<128, false, false, true><<<dim3(BATCH), dim3(512), 0, stream>>>(
      Wih1, Whh1, bih1, bhh1, h0, nullptr, Wlin, blin, (float*)d_out);
}

// Round 2
// 3400.090 us; speedup vs baseline: 1.2116x; 1.2116x over previous
//
#include <hip/hip_runtime.h>

#define SEQ_T 2048
#define BATCH 64

typedef _Float16 half2v __attribute__((ext_vector_type(2)));

#if defined(__has_builtin)
#  if __has_builtin(__builtin_amdgcn_fdot2)
#    define HAVE_FDOT2 1
#  endif
#endif

__device__ __forceinline__ float fdot2f(half2v a, half2v b, float c) {
#ifdef HAVE_FDOT2
  return __builtin_amdgcn_fdot2(a, b, c, false);
#else
  return c + (float)a[0] * (float)b[0] + (float)a[1] * (float)b[1];
#endif
}

__device__ __forceinline__ unsigned int h2u(half2v v) { return __builtin_bit_cast(unsigned int, v); }
__device__ __forceinline__ half2v u2h(unsigned int u) { return __builtin_bit_cast(half2v, u); }

__device__ __forceinline__ float sigmoid_fast(float x) {
  return 1.f / (1.f + __expf(-x));
}
__device__ __forceinline__ float tanh_fast(float x) {
  return 1.f - 2.f / (1.f + __expf(2.f * x));
}

// ---------------------------------------------------------------------------
// xproj GEMM: xp[tb][r*4+ks] = f16( X[tb][:]·W[g][:] + bih[g]+bhh[g] ),
// where g = ks*128+r (gate-interleaved layout so the recurrent kernel's
// per-step load is one coalesced ushort per thread).
// Block: 512 threads, one gate column each; M-tile = 64 tb rows staged in LDS.
// ---------------------------------------------------------------------------
template <int K, bool IN_F32>
__global__ __launch_bounds__(512) void xproj_gemm(
    const void* __restrict__ Xv,            // [M][K] f32 or f16
    const float* __restrict__ W,            // [512][K] f32
    const float* __restrict__ bih, const float* __restrict__ bhh,
    unsigned short* __restrict__ xp)        // [M][512] f16, gate-interleaved
{
  constexpr int MT = 64;
  const int g = threadIdx.x;
  const size_t m0 = (size_t)blockIdx.x * MT;

  __shared__ __align__(16) _Float16 xs[MT * K];

  // stage X tile as f16
  if constexpr (IN_F32) {
    constexpr int PER = MT * K / 512;       // 8 for K=64
    const float* Xf = (const float*)Xv + m0 * K + (size_t)g * PER;
    _Float16* dst = xs + g * PER;
#pragma unroll
    for (int i = 0; i < PER; i += 4) {
      float4 v = *reinterpret_cast<const float4*>(Xf + i);
      half2v h01; h01[0] = (_Float16)v.x; h01[1] = (_Float16)v.y;
      half2v h23; h23[0] = (_Float16)v.z; h23[1] = (_Float16)v.w;
      uint2 u; u.x = h2u(h01); u.y = h2u(h23);
      *reinterpret_cast<uint2*>(dst + i) = u;
    }
  } else {
    constexpr int PER = MT * K / 512;       // 16 for K=128
    const unsigned short* Xh = (const unsigned short*)Xv + m0 * K + (size_t)g * PER;
#pragma unroll
    for (int i = 0; i < PER / 8; i++)
      reinterpret_cast<uint4*>(xs + g * PER)[i] = reinterpret_cast<const uint4*>(Xh)[i];
  }

  // W row -> f16 register pairs
  half2v wr[K / 2];
  {
    const float2* p = reinterpret_cast<const float2*>(W + (size_t)g * K);
#pragma unroll
    for (int k = 0; k < K / 2; k++) {
      float2 f = p[k];
      half2v v; v[0] = (_Float16)f.x; v[1] = (_Float16)f.y;
      wr[k] = v;
    }
  }
  const float bias = bih[g] + bhh[g];
  const int out_off = (g & 127) * 4 + (g >> 7);
  __syncthreads();

#pragma unroll 1
  for (int tb = 0; tb < MT; tb++) {
    const uint4* xv = reinterpret_cast<const uint4*>(xs + tb * K);
    float a0 = bias, a1 = 0.f, a2 = 0.f, a3 = 0.f;
#pragma unroll
    for (int i = 0; i < K / 8; i++) {
      const uint4 u = xv[i];
      a0 = fdot2f(wr[4 * i + 0], u2h(u.x), a0);
      a1 = fdot2f(wr[4 * i + 1], u2h(u.y), a1);
      a2 = fdot2f(wr[4 * i + 2], u2h(u.z), a2);
      a3 = fdot2f(wr[4 * i + 3], u2h(u.w), a3);
    }
    const float s = (a0 + a1) + (a2 + a3);
    xp[(m0 + tb) * 512 + out_off] = __builtin_bit_cast(unsigned short, (_Float16)s);
  }
}

// ---------------------------------------------------------------------------
// Recurrence: one WG per batch element, 512 threads.
// lane l: rr=l>>2 (row-in-wave), ks=l&3 (K-split); row r = wave*16+rr.
// Each thread: 4 gate partials over h[ks*32 .. ks*32+32); xp seeded into
// accumulator ks; butterfly over lanes xor{1,2} completes all 4 gate sums in
// every lane; c,h computed redundantly per 4-lane group. One barrier/step.
// ---------------------------------------------------------------------------
__global__ __launch_bounds__(512) void lstm_rec2(
    const float* __restrict__ Whh,          // [512][128] f32
    const unsigned short* __restrict__ xp,  // [T*B][512] f16 gate-interleaved
    unsigned short* __restrict__ hout)      // [T*B][128] f16
{
  const int b = blockIdx.x;
  const int tid = threadIdx.x;
  const int l = tid & 63;
  const int w = tid >> 6;
  const int rr = l >> 2;
  const int ks = l & 3;
  const int r = w * 16 + rr;

  __shared__ __align__(16) _Float16 hbuf[2][128];

  // Whh rows for this thread's 4 gates, K-chunk ks*32..+32, as f16 pairs
  half2v wh[4][16];
#pragma unroll
  for (int g = 0; g < 4; g++) {
    const float2* p = reinterpret_cast<const float2*>(
        Whh + ((size_t)(g * 128 + r)) * 128 + ks * 32);
#pragma unroll
    for (int k = 0; k < 16; k++) {
      float2 f = p[k];
      half2v v; v[0] = (_Float16)f.x; v[1] = (_Float16)f.y;
      wh[g][k] = v;
    }
  }

  if (tid < 128) hbuf[0][tid] = (_Float16)0.f;

  const unsigned short* xpb = xp + (size_t)b * 512 + tid;  // coalesced: offset == tid
  float xp_cur = 0.f;
  {
    unsigned short u = xpb[0];
    xp_cur = (float)__builtin_bit_cast(_Float16, u);
  }
  float c = 0.f;
  __syncthreads();

  for (int t = 0; t < SEQ_T; ++t) {
    const int cur = t & 1;

    // prefetch next timestep's xp (consumed after this step's compute)
    unsigned short xpn_bits;
    {
      const int tn = (t + 1 < SEQ_T) ? (t + 1) : t;
      xpn_bits = xpb[(size_t)tn * (BATCH * 512)];
    }

    float a0 = (ks == 0) ? xp_cur : 0.f;
    float a1 = (ks == 1) ? xp_cur : 0.f;
    float a2 = (ks == 2) ? xp_cur : 0.f;
    float a3 = (ks == 3) ? xp_cur : 0.f;

    const uint4* hv = reinterpret_cast<const uint4*>(&hbuf[cur][0]);
#pragma unroll
    for (int i = 0; i < 4; i++) {
      const uint4 u = hv[ks * 4 + i];
      a0 = fdot2f(wh[0][4 * i + 0], u2h(u.x), a0);
      a0 = fdot2f(wh[0][4 * i + 1], u2h(u.y), a0);
      a0 = fdot2f(wh[0][4 * i + 2], u2h(u.z), a0);
      a0 = fdot2f(wh[0][4 * i + 3], u2h(u.w), a0);
      a1 = fdot2f(wh[1][4 * i + 0], u2h(u.x), a1);
      a1 = fdot2f(wh[1][4 * i + 1], u2h(u.y), a1);
      a1 = fdot2f(wh[1][4 * i + 2], u2h(u.z), a1);
      a1 = fdot2f(wh[1][4 * i + 3], u2h(u.w), a1);
      a2 = fdot2f(wh[2][4 * i + 0], u2h(u.x), a2);
      a2 = fdot2f(wh[2][4 * i + 1], u2h(u.y), a2);
      a2 = fdot2f(wh[2][4 * i + 2], u2h(u.z), a2);
      a2 = fdot2f(wh[2][4 * i + 3], u2h(u.w), a2);
      a3 = fdot2f(wh[3][4 * i + 0], u2h(u.x), a3);
      a3 = fdot2f(wh[3][4 * i + 1], u2h(u.y), a3);
      a3 = fdot2f(wh[3][4 * i + 2], u2h(u.z), a3);
      a3 = fdot2f(wh[3][4 * i + 3], u2h(u.w), a3);
    }

    // butterfly across the 4-lane K-split group: all lanes get full gate sums
    a0 += __shfl_xor(a0, 1); a0 += __shfl_xor(a0, 2);
    a1 += __shfl_xor(a1, 1); a1 += __shfl_xor(a1, 2);
    a2 += __shfl_xor(a2, 1); a2 += __shfl_xor(a2, 2);
    a3 += __shfl_xor(a3, 1); a3 += __shfl_xor(a3, 2);

    const float gi = sigmoid_fast(a0);
    const float gf = sigmoid_fast(a1);
    const float gg = tanh_fast(a2);
    const float go = sigmoid_fast(a3);
    c = gf * c + gi * gg;
    const float h = go * tanh_fast(c);

    if (ks == 0) {
      hbuf[cur ^ 1][r] = (_Float16)h;
      hout[((size_t)t * BATCH + b) * 128 + r] =
          __builtin_bit_cast(unsigned short, (_Float16)h);
    }
    xp_cur = (float)__builtin_bit_cast(_Float16, xpn_bits);
    __syncthreads();
  }
}

// ---------------------------------------------------------------------------
// Final linear: out[tb] = h1[tb]·wlin + blin
// ---------------------------------------------------------------------------
__global__ __launch_bounds__(256) void final_lin(
    const unsigned short* __restrict__ h1,  // [T*B][128] f16
    const float* __restrict__ Wlin, const float* __restrict__ blin,
    float* __restrict__ out)
{
  const size_t tb = (size_t)blockIdx.x * 256 + threadIdx.x;
  half2v wl[64];
  const float2* p = reinterpret_cast<const float2*>(Wlin);
#pragma unroll
  for (int k = 0; k < 64; k++) {
    float2 f = p[k];
    half2v v; v[0] = (_Float16)f.x; v[1] = (_Float16)f.y;
    wl[k] = v;
  }
  const uint4* hv = reinterpret_cast<const uint4*>(h1 + tb * 128);
  float a0 = 0.f, a1 = 0.f, a2 = 0.f, a3 = 0.f;
#pragma unroll
  for (int i = 0; i < 16; i++) {
    const uint4 u = hv[i];
    a0 = fdot2f(wl[4 * i + 0], u2h(u.x), a0);
    a1 = fdot2f(wl[4 * i + 1], u2h(u.y), a1);
    a2 = fdot2f(wl[4 * i + 2], u2h(u.z), a2);
    a3 = fdot2f(wl[4 * i + 3], u2h(u.w), a3);
  }
  out[tb] = (a0 + a1) + (a2 + a3) + blin[0];
}

extern "C" void kernel_launch(void* const* d_in, const int* in_sizes, int n_in,
                              void* d_out, int out_size, void* d_ws, size_t ws_size,
                              hipStream_t stream) {
  (void)in_sizes; (void)n_in; (void)out_size; (void)ws_size;

  const float* data = (const float*)d_in[0];
  const float* Wih0 = (const float*)d_in[1];
  const float* Whh0 = (const float*)d_in[2];
  const float* bih0 = (const float*)d_in[3];
  const float* bhh0 = (const float*)d_in[4];
  const float* Wih1 = (const float*)d_in[5];
  const float* Whh1 = (const float*)d_in[6];
  const float* bih1 = (const float*)d_in[7];
  const float* bhh1 = (const float*)d_in[8];
  const float* Wlin = (const float*)d_in[9];
  const float* blin = (const float*)d_in[10];

  // ws layout: xp 128 MiB | h0 32 MiB | h1 32 MiB  (192 MiB total)
  unsigned char* ws = (unsigned char*)d_ws;
  unsigned short* xpb = (unsigned short*)ws;
  unsigned short* h0 = (unsigned short*)(ws + (size_t)128 * 1024 * 1024);
  unsigned short* h1 = (unsigned short*)(ws + (size_t)160 * 1024 * 1024);

  const int M = SEQ_T * BATCH;        // 131072
  const int gemm_blocks = M / 64;     // 2048

  xproj_gemm<64, true><<<dim3(gemm_blocks), dim3(512), 0, stream>>>(
      data, Wih0, bih0, bhh0, xpb);
  lstm_rec2<<<dim3(BATCH), dim3(512), 0, stream>>>(Whh0, xpb, h0);
  xproj_gemm<128, false><<<dim3(gemm_blocks), dim3(512), 0, stream>>>(
      h0, Wih1, bih1, bhh1, xpb);
  lstm_rec2<<<dim3(BATCH), dim3(512), 0, stream>>>(Whh1, xpb, h1);
  final_lin<<<dim3(M / 256), dim3(256), 0, stream>>>(h1, Wlin, blin, (float*)d_out);
}

// Round 3
// 3399.387 us; speedup vs baseline: 1.2118x; 1.0002x over previous
//
#include <hip/hip_runtime.h>

#define SEQ_T 2048
#define BATCH 64

typedef _Float16 half2v __attribute__((ext_vector_type(2)));

#if defined(__has_builtin)
#  if __has_builtin(__builtin_amdgcn_fdot2)
#    define HAVE_FDOT2 1
#  endif
#endif

__device__ __forceinline__ float fdot2f(half2v a, half2v b, float c) {
#ifdef HAVE_FDOT2
  return __builtin_amdgcn_fdot2(a, b, c, false);
#else
  return c + (float)a[0] * (float)b[0] + (float)a[1] * (float)b[1];
#endif
}

__device__ __forceinline__ unsigned int h2u(half2v v) { return __builtin_bit_cast(unsigned int, v); }
__device__ __forceinline__ half2v u2h(unsigned int u) { return __builtin_bit_cast(half2v, u); }

__device__ __forceinline__ float sigmoid_fast(float x) {
  return 1.f / (1.f + __expf(-x));
}
__device__ __forceinline__ float tanh_fast(float x) {
  return 1.f - 2.f / (1.f + __expf(2.f * x));
}

// ---------------------------------------------------------------------------
// xproj GEMM: xp[tb][r*4+ks] = f16( X[tb][:]·W[g][:] + bih[g]+bhh[g] ),
// g = ks*128+r (gate-interleaved so the recurrent per-step load is one
// coalesced ushort per thread).
// ---------------------------------------------------------------------------
template <int K, bool IN_F32>
__global__ __launch_bounds__(512) void xproj_gemm(
    const void* __restrict__ Xv,            // [M][K] f32 or f16
    const float* __restrict__ W,            // [512][K] f32
    const float* __restrict__ bih, const float* __restrict__ bhh,
    unsigned short* __restrict__ xp)        // [M][512] f16, gate-interleaved
{
  constexpr int MT = 64;
  const int g = threadIdx.x;
  const size_t m0 = (size_t)blockIdx.x * MT;

  __shared__ __align__(16) _Float16 xs[MT * K];

  if constexpr (IN_F32) {
    constexpr int PER = MT * K / 512;
    const float* Xf = (const float*)Xv + m0 * K + (size_t)g * PER;
    _Float16* dst = xs + g * PER;
#pragma unroll
    for (int i = 0; i < PER; i += 4) {
      float4 v = *reinterpret_cast<const float4*>(Xf + i);
      half2v h01; h01[0] = (_Float16)v.x; h01[1] = (_Float16)v.y;
      half2v h23; h23[0] = (_Float16)v.z; h23[1] = (_Float16)v.w;
      uint2 u; u.x = h2u(h01); u.y = h2u(h23);
      *reinterpret_cast<uint2*>(dst + i) = u;
    }
  } else {
    constexpr int PER = MT * K / 512;
    const unsigned short* Xh = (const unsigned short*)Xv + m0 * K + (size_t)g * PER;
#pragma unroll
    for (int i = 0; i < PER / 8; i++)
      reinterpret_cast<uint4*>(xs + g * PER)[i] = reinterpret_cast<const uint4*>(Xh)[i];
  }

  half2v wr[K / 2];
  {
    const float2* p = reinterpret_cast<const float2*>(W + (size_t)g * K);
#pragma unroll
    for (int k = 0; k < K / 2; k++) {
      float2 f = p[k];
      half2v v; v[0] = (_Float16)f.x; v[1] = (_Float16)f.y;
      wr[k] = v;
    }
  }
  const float bias = bih[g] + bhh[g];
  const int out_off = (g & 127) * 4 + (g >> 7);
  __syncthreads();

#pragma unroll 1
  for (int tb = 0; tb < MT; tb++) {
    const uint4* xv = reinterpret_cast<const uint4*>(xs + tb * K);
    float a0 = bias, a1 = 0.f, a2 = 0.f, a3 = 0.f;
#pragma unroll
    for (int i = 0; i < K / 8; i++) {
      const uint4 u = xv[i];
      a0 = fdot2f(wr[4 * i + 0], u2h(u.x), a0);
      a1 = fdot2f(wr[4 * i + 1], u2h(u.y), a1);
      a2 = fdot2f(wr[4 * i + 2], u2h(u.z), a2);
      a3 = fdot2f(wr[4 * i + 3], u2h(u.w), a3);
    }
    const float s = (a0 + a1) + (a2 + a3);
    xp[(m0 + tb) * 512 + out_off] = __builtin_bit_cast(unsigned short, (_Float16)s);
  }
}

// ---------------------------------------------------------------------------
// Recurrence: one WG per batch element, 512 threads.
// thread = (row r = wave*16 + (l>>2), K-split ks = l&3). 64 dot2/thread/step;
// 2-round quad butterfly completes all 4 gate sums; c,h redundant per group.
// ONE raw barrier per step (lgkmcnt drain only — prefetch loads and hout
// stores stay in flight across it). xp prefetched 2 steps deep.
// ---------------------------------------------------------------------------
__device__ __forceinline__ void lstm_step(
    int t, int cur, int ks, int r, int b,
    const half2v (&wh)[4][16], _Float16 (&hbuf)[2][128],
    unsigned short& pf, const unsigned short* __restrict__ xpb,
    float& c, unsigned short* __restrict__ hout)
{
  // consume the 2-steps-ago prefetch, immediately re-issue for t+2
  const float xpv = (float)__builtin_bit_cast(_Float16, pf);
  const int tn = (t + 2 < SEQ_T) ? (t + 2) : (SEQ_T - 1);
  pf = xpb[(size_t)tn * (BATCH * 512)];

  float a0 = (ks == 0) ? xpv : 0.f;
  float a1 = (ks == 1) ? xpv : 0.f;
  float a2 = (ks == 2) ? xpv : 0.f;
  float a3 = (ks == 3) ? xpv : 0.f;

  const uint4* hv = reinterpret_cast<const uint4*>(&hbuf[cur][0]);
#pragma unroll
  for (int i = 0; i < 4; i++) {
    const uint4 u = hv[ks * 4 + i];
    a0 = fdot2f(wh[0][4 * i + 0], u2h(u.x), a0);
    a0 = fdot2f(wh[0][4 * i + 1], u2h(u.y), a0);
    a0 = fdot2f(wh[0][4 * i + 2], u2h(u.z), a0);
    a0 = fdot2f(wh[0][4 * i + 3], u2h(u.w), a0);
    a1 = fdot2f(wh[1][4 * i + 0], u2h(u.x), a1);
    a1 = fdot2f(wh[1][4 * i + 1], u2h(u.y), a1);
    a1 = fdot2f(wh[1][4 * i + 2], u2h(u.z), a1);
    a1 = fdot2f(wh[1][4 * i + 3], u2h(u.w), a1);
    a2 = fdot2f(wh[2][4 * i + 0], u2h(u.x), a2);
    a2 = fdot2f(wh[2][4 * i + 1], u2h(u.y), a2);
    a2 = fdot2f(wh[2][4 * i + 2], u2h(u.z), a2);
    a2 = fdot2f(wh[2][4 * i + 3], u2h(u.w), a2);
    a3 = fdot2f(wh[3][4 * i + 0], u2h(u.x), a3);
    a3 = fdot2f(wh[3][4 * i + 1], u2h(u.y), a3);
    a3 = fdot2f(wh[3][4 * i + 2], u2h(u.z), a3);
    a3 = fdot2f(wh[3][4 * i + 3], u2h(u.w), a3);
  }

  a0 += __shfl_xor(a0, 1); a0 += __shfl_xor(a0, 2);
  a1 += __shfl_xor(a1, 1); a1 += __shfl_xor(a1, 2);
  a2 += __shfl_xor(a2, 1); a2 += __shfl_xor(a2, 2);
  a3 += __shfl_xor(a3, 1); a3 += __shfl_xor(a3, 2);

  const float gi = sigmoid_fast(a0);
  const float gf = sigmoid_fast(a1);
  const float gg = tanh_fast(a2);
  const float go = sigmoid_fast(a3);
  c = gf * c + gi * gg;
  const float h = go * tanh_fast(c);

  if (ks == 0) {
    hbuf[cur ^ 1][r] = (_Float16)h;
    hout[((size_t)t * BATCH + b) * 128 + r] =
        __builtin_bit_cast(unsigned short, (_Float16)h);
  }
  // raw barrier: order only the LDS write/reads; loads+stores stay in flight
  asm volatile("s_waitcnt lgkmcnt(0)" ::: "memory");
  __builtin_amdgcn_s_barrier();
}

__global__ __launch_bounds__(512, 2) void lstm_rec2(
    const float* __restrict__ Whh,          // [512][128] f32
    const unsigned short* __restrict__ xp,  // [T*B][512] f16 gate-interleaved
    unsigned short* __restrict__ hout)      // [T*B][128] f16
{
  const int b = blockIdx.x;
  const int tid = threadIdx.x;
  const int l = tid & 63;
  const int w = tid >> 6;
  const int rr = l >> 2;
  const int ks = l & 3;
  const int r = w * 16 + rr;

  __shared__ __align__(16) _Float16 hbuf[2][128];

  half2v wh[4][16];
#pragma unroll
  for (int g = 0; g < 4; g++) {
    const float2* p = reinterpret_cast<const float2*>(
        Whh + ((size_t)(g * 128 + r)) * 128 + ks * 32);
#pragma unroll
    for (int k = 0; k < 16; k++) {
      float2 f = p[k];
      half2v v; v[0] = (_Float16)f.x; v[1] = (_Float16)f.y;
      wh[g][k] = v;
    }
  }

  if (tid < 128) hbuf[0][tid] = (_Float16)0.f;

  const unsigned short* xpb = xp + (size_t)b * 512 + tid;
  unsigned short pfa = xpb[0];
  unsigned short pfb = xpb[(size_t)1 * (BATCH * 512)];
  float c = 0.f;
  __syncthreads();

#pragma unroll 1
  for (int t = 0; t < SEQ_T; t += 2) {
    lstm_step(t,     0, ks, r, b, wh, hbuf, pfa, xpb, c, hout);
    lstm_step(t + 1, 1, ks, r, b, wh, hbuf, pfb, xpb, c, hout);
  }
}

// ---------------------------------------------------------------------------
// Final linear: out[tb] = h1[tb]·wlin + blin
// ---------------------------------------------------------------------------
__global__ __launch_bounds__(256) void final_lin(
    const unsigned short* __restrict__ h1,  // [T*B][128] f16
    const float* __restrict__ Wlin, const float* __restrict__ blin,
    float* __restrict__ out)
{
  const size_t tb = (size_t)blockIdx.x * 256 + threadIdx.x;
  half2v wl[64];
  const float2* p = reinterpret_cast<const float2*>(Wlin);
#pragma unroll
  for (int k = 0; k < 64; k++) {
    float2 f = p[k];
    half2v v; v[0] = (_Float16)f.x; v[1] = (_Float16)f.y;
    wl[k] = v;
  }
  const uint4* hv = reinterpret_cast<const uint4*>(h1 + tb * 128);
  float a0 = 0.f, a1 = 0.f, a2 = 0.f, a3 = 0.f;
#pragma unroll
  for (int i = 0; i < 16; i++) {
    const uint4 u = hv[i];
    a0 = fdot2f(wl[4 * i + 0], u2h(u.x), a0);
    a1 = fdot2f(wl[4 * i + 1], u2h(u.y), a1);
    a2 = fdot2f(wl[4 * i + 2], u2h(u.z), a2);
    a3 = fdot2f(wl[4 * i + 3], u2h(u.w), a3);
  }
  out[tb] = (a0 + a1) + (a2 + a3) + blin[0];
}

extern "C" void kernel_launch(void* const* d_in, const int* in_sizes, int n_in,
                              void* d_out, int out_size, void* d_ws, size_t ws_size,
                              hipStream_t stream) {
  (void)in_sizes; (void)n_in; (void)out_size; (void)ws_size;

  const float* data = (const float*)d_in[0];
  const float* Wih0 = (const float*)d_in[1];
  const float* Whh0 = (const float*)d_in[2];
  const float* bih0 = (const float*)d_in[3];
  const float* bhh0 = (const float*)d_in[4];
  const float* Wih1 = (const float*)d_in[5];
  const float* Whh1 = (const float*)d_in[6];
  const float* bih1 = (const float*)d_in[7];
  const float* bhh1 = (const float*)d_in[8];
  const float* Wlin = (const float*)d_in[9];
  const float* blin = (const float*)d_in[10];

  // ws layout: xp 128 MiB | h0 32 MiB | h1 32 MiB
  unsigned char* ws = (unsigned char*)d_ws;
  unsigned short* xpb = (unsigned short*)ws;
  unsigned short* h0 = (unsigned short*)(ws + (size_t)128 * 1024 * 1024);
  unsigned short* h1 = (unsigned short*)(ws + (size_t)160 * 1024 * 1024);

  const int M = SEQ_T * BATCH;
  const int gemm_blocks = M / 64;

  xproj_gemm<64, true><<<dim3(gemm_blocks), dim3(512), 0, stream>>>(
      data, Wih0, bih0, bhh0, xpb);
  lstm_rec2<<<dim3(BATCH), dim3(512), 0, stream>>>(Whh0, xpb, h0);
  xproj_gemm<128, false><<<dim3(gemm_blocks), dim3(512), 0, stream>>>(
      h0, Wih1, bih1, bhh1, xpb);
  lstm_rec2<<<dim3(BATCH), dim3(512), 0, stream>>>(Whh1, xpb, h1);
  final_lin<<<dim3(M / 256), dim3(256), 0, stream>>>(h1, Wlin, blin, (float*)d_out);
}

// Round 6
// 3194.896 us; speedup vs baseline: 1.2894x; 1.0640x over previous
//
#include <hip/hip_runtime.h>

#define SEQ_T 2048
#define BATCH 64

typedef _Float16 half2v __attribute__((ext_vector_type(2)));
typedef float floatx2 __attribute__((ext_vector_type(2)));

#if defined(__has_builtin)
#  if __has_builtin(__builtin_amdgcn_fdot2)
#    define HAVE_FDOT2 1
#  endif
#endif

// f16-pair dot with f32 accumulate — R1-R3-proven path (builtin or exact-f32
// fallback). NOTE: inline-asm v_dot2_f32_f16 gave ~0.1 absmax on gfx950 (R4/R5)
// — do not use it.
__device__ __forceinline__ float fdot2f(half2v a, half2v b, float c) {
#ifdef HAVE_FDOT2
  return __builtin_amdgcn_fdot2(a, b, c, false);
#else
  return c + (float)a[0] * (float)b[0] + (float)a[1] * (float)b[1];
#endif
}

__device__ __forceinline__ floatx2 fma2(floatx2 a, floatx2 b, floatx2 c) {
#if __has_builtin(__builtin_elementwise_fma)
  return __builtin_elementwise_fma(a, b, c);
#else
  floatx2 r;
  r.x = __builtin_fmaf(a.x, b.x, c.x);
  r.y = __builtin_fmaf(a.y, b.y, c.y);
  return r;
#endif
}

__device__ __forceinline__ unsigned int h2u(half2v v) { return __builtin_bit_cast(unsigned int, v); }
__device__ __forceinline__ half2v u2h(unsigned int u) { return __builtin_bit_cast(half2v, u); }

// ---------------------------------------------------------------------------
// xproj GEMM: xp[tb][r*4+g] = f16( X[tb][:]·W[g*128+r][:] + bih+bhh ) —
// gate-interleaved so the recurrent per-step load is one coalesced ushort.
// (identical to the R2/R3-proven kernel)
// ---------------------------------------------------------------------------
template <int K, bool IN_F32>
__global__ __launch_bounds__(512) void xproj_gemm(
    const void* __restrict__ Xv,            // [M][K] f32 or f16
    const float* __restrict__ W,            // [512][K] f32
    const float* __restrict__ bih, const float* __restrict__ bhh,
    unsigned short* __restrict__ xp)        // [M][512] f16, gate-interleaved
{
  constexpr int MT = 64;
  const int g = threadIdx.x;
  const size_t m0 = (size_t)blockIdx.x * MT;

  __shared__ __align__(16) _Float16 xs[MT * K];

  if constexpr (IN_F32) {
    constexpr int PER = MT * K / 512;
    const float* Xf = (const float*)Xv + m0 * K + (size_t)g * PER;
    _Float16* dst = xs + g * PER;
#pragma unroll
    for (int i = 0; i < PER; i += 4) {
      float4 v = *reinterpret_cast<const float4*>(Xf + i);
      half2v h01; h01[0] = (_Float16)v.x; h01[1] = (_Float16)v.y;
      half2v h23; h23[0] = (_Float16)v.z; h23[1] = (_Float16)v.w;
      uint2 u; u.x = h2u(h01); u.y = h2u(h23);
      *reinterpret_cast<uint2*>(dst + i) = u;
    }
  } else {
    constexpr int PER = MT * K / 512;
    const unsigned short* Xh = (const unsigned short*)Xv + m0 * K + (size_t)g * PER;
#pragma unroll
    for (int i = 0; i < PER / 8; i++)
      reinterpret_cast<uint4*>(xs + g * PER)[i] = reinterpret_cast<const uint4*>(Xh)[i];
  }

  half2v wr[K / 2];
  {
    const float2* p = reinterpret_cast<const float2*>(W + (size_t)g * K);
#pragma unroll
    for (int k = 0; k < K / 2; k++) {
      float2 f = p[k];
      half2v v; v[0] = (_Float16)f.x; v[1] = (_Float16)f.y;
      wr[k] = v;
    }
  }
  const float bias = bih[g] + bhh[g];
  const int out_off = (g & 127) * 4 + (g >> 7);
  __syncthreads();

#pragma unroll 1
  for (int tb = 0; tb < MT; tb++) {
    const uint4* xv = reinterpret_cast<const uint4*>(xs + tb * K);
    float a0 = bias, a1 = 0.f, a2 = 0.f, a3 = 0.f;
#pragma unroll
    for (int i = 0; i < K / 8; i++) {
      const uint4 u = xv[i];
      a0 = fdot2f(wr[4 * i + 0], u2h(u.x), a0);
      a1 = fdot2f(wr[4 * i + 1], u2h(u.y), a1);
      a2 = fdot2f(wr[4 * i + 2], u2h(u.z), a2);
      a3 = fdot2f(wr[4 * i + 3], u2h(u.w), a3);
    }
    const float s = (a0 + a1) + (a2 + a3);
    xp[(m0 + tb) * 512 + out_off] = __builtin_bit_cast(unsigned short, (_Float16)s);
  }
}

// ---------------------------------------------------------------------------
// Recurrence: one WG per batch element, 512 threads. FULL F32 datapath.
// thread = (row r = wave*16 + (l>>2), K-split ks = l&3); each thread: 4 gate
// partials over h-chunk ks (32 f32 elems) with exact f32 FMA (packable to
// v_pk_fma_f32). Quad reduce-scatter (3 shfl) -> ONE activation per lane ->
// quad all-gather (4 shfl) -> redundant c/h update. __syncthreads per step.
// hbuf is chunk-skewed (stride 36 floats) so the 4 ks-quadrant float4 reads
// hit disjoint bank windows (conflict-free).
// ---------------------------------------------------------------------------
struct StepCtx {
  int ks, r, hidx;              // hidx = skewed LDS index for writer
  int li0, li1, li2, li3;       // quad lane ids for all-gather
  float sc, am, ab;             // activation: y = am*sigmoid(sc*x)+ab
  bool writer;
};

__device__ __forceinline__ float sigmoid_fast(float x) {
  return 1.f / (1.f + __expf(-x));
}

__device__ __forceinline__ void lstm_step(
    int cur, const StepCtx& cx,
    const floatx2 (&wh)[4][16], float (&hbuf)[2][144],
    unsigned short& pf, const unsigned short*& pf_ptr,
    float& c, unsigned short*& hout_ptr)
{
  // consume 2-steps-ago prefetch; immediately re-issue 2 ahead
  const float xpv = (float)__builtin_bit_cast(_Float16, pf);
  pf = *pf_ptr;
  pf_ptr += 2 * BATCH * 512;

  floatx2 a0 = {0.f, 0.f}, a1 = {0.f, 0.f}, a2 = {0.f, 0.f}, a3 = {0.f, 0.f};
  const float4* hv = reinterpret_cast<const float4*>(&hbuf[cur][cx.ks * 36]);
#pragma unroll
  for (int i = 0; i < 8; i++) {
    const float4 u = hv[i];
    floatx2 lo; lo.x = u.x; lo.y = u.y;
    floatx2 hi; hi.x = u.z; hi.y = u.w;
    a0 = fma2(wh[0][2 * i], lo, a0); a0 = fma2(wh[0][2 * i + 1], hi, a0);
    a1 = fma2(wh[1][2 * i], lo, a1); a1 = fma2(wh[1][2 * i + 1], hi, a1);
    a2 = fma2(wh[2][2 * i], lo, a2); a2 = fma2(wh[2][2 * i + 1], hi, a2);
    a3 = fma2(wh[3][2 * i], lo, a3); a3 = fma2(wh[3][2 * i + 1], hi, a3);
  }
  float b0v = a0.x + a0.y;
  float b1v = a1.x + a1.y;
  float b2v = a2.x + a2.y;
  float b3v = a3.x + a3.y;

  // quad reduce-scatter: lane ks ends with the full sum of gate ks
  const bool q0 = (cx.ks & 1) != 0, q1 = (cx.ks & 2) != 0;
  float s0 = q0 ? b0v : b1v;
  float s1 = q0 ? b2v : b3v;
  float r0 = __shfl_xor(s0, 1);
  float r1 = __shfl_xor(s1, 1);
  float kA = (q0 ? b1v : b0v) + r0;   // gate q0 over chunk pair
  float kB = (q0 ? b3v : b2v) + r1;   // gate q0+2 over chunk pair
  float s2 = q1 ? kA : kB;
  float r2 = __shfl_xor(s2, 2);
  float sum = (q1 ? kB : kA) + r2 + xpv;

  // ONE activation per lane: y = am * sigmoid(sc*sum) + ab
  float y = cx.am * sigmoid_fast(cx.sc * sum) + cx.ab;

  // all-gather activated gates across the quad
  float gi = __shfl(y, cx.li0);
  float gf = __shfl(y, cx.li1);
  float gg = __shfl(y, cx.li2);
  float go = __shfl(y, cx.li3);

  c = gf * c + gi * gg;
  float th = 2.f * sigmoid_fast(2.f * c) - 1.f;
  float h = go * th;

  if (cx.writer) {
    hbuf[cur ^ 1][cx.hidx] = h;
    *hout_ptr = __builtin_bit_cast(unsigned short, (_Float16)h);
  }
  hout_ptr += BATCH * 128;

  __syncthreads();
}

__global__ __launch_bounds__(512, 2) void lstm_rec2(
    const float* __restrict__ Whh,          // [512][128] f32
    const unsigned short* __restrict__ xp,  // [T*B][512] f16 gate-interleaved
    unsigned short* __restrict__ hout)      // [T*B][128] f16
{
  const int b = blockIdx.x;
  const int tid = threadIdx.x;
  const int l = tid & 63;
  const int w = tid >> 6;
  const int rr = l >> 2;
  const int ks = l & 3;
  const int r = w * 16 + rr;

  __shared__ __align__(16) float hbuf[2][144];   // 4 chunks x 36 (skewed)

  // Whh rows for this thread's 4 gates, chunk ks*32..+32, as f32 pairs
  floatx2 wh[4][16];
#pragma unroll
  for (int g = 0; g < 4; g++) {
    const float4* p = reinterpret_cast<const float4*>(
        Whh + ((size_t)(g * 128 + r)) * 128 + ks * 32);
#pragma unroll
    for (int k = 0; k < 8; k++) {
      float4 f = p[k];
      floatx2 lo; lo.x = f.x; lo.y = f.y;
      floatx2 hi; hi.x = f.z; hi.y = f.w;
      wh[g][2 * k] = lo;
      wh[g][2 * k + 1] = hi;
    }
  }

  StepCtx cx;
  cx.ks = ks; cx.r = r;
  cx.hidx = (r >> 5) * 36 + (r & 31);
  const int lb = l & ~3;
  cx.li0 = lb + 0; cx.li1 = lb + 1; cx.li2 = lb + 2; cx.li3 = lb + 3;
  cx.sc = (ks == 2) ? 2.f : 1.f;
  cx.am = (ks == 2) ? 2.f : 1.f;
  cx.ab = (ks == 2) ? -1.f : 0.f;
  cx.writer = (ks == 0);

  if (tid < 144) { hbuf[0][tid] = 0.f; }

  const unsigned short* xpb = xp + (size_t)b * 512 + tid;  // tid == r*4+ks
  unsigned short pfa = xpb[0];
  unsigned short pfb = xpb[(size_t)1 * (BATCH * 512)];
  const unsigned short* pA = xpb + (size_t)2 * (BATCH * 512);
  const unsigned short* pB = xpb + (size_t)3 * (BATCH * 512);
  unsigned short* houtp = hout + (size_t)b * 128 + r;
  float c = 0.f;
  __syncthreads();

#pragma unroll 1
  for (int t = 0; t < SEQ_T; t += 2) {
    lstm_step(0, cx, wh, hbuf, pfa, pA, c, houtp);
    lstm_step(1, cx, wh, hbuf, pfb, pB, c, houtp);
  }
}

// ---------------------------------------------------------------------------
// Final linear: out[tb] = h1[tb]·wlin + blin  (R3-proven)
// ---------------------------------------------------------------------------
__global__ __launch_bounds__(256) void final_lin(
    const unsigned short* __restrict__ h1,  // [T*B][128] f16
    const float* __restrict__ Wlin, const float* __restrict__ blin,
    float* __restrict__ out)
{
  const size_t tb = (size_t)blockIdx.x * 256 + threadIdx.x;
  half2v wl[64];
  const float2* p = reinterpret_cast<const float2*>(Wlin);
#pragma unroll
  for (int k = 0; k < 64; k++) {
    float2 f = p[k];
    half2v v; v[0] = (_Float16)f.x; v[1] = (_Float16)f.y;
    wl[k] = v;
  }
  const uint4* hv = reinterpret_cast<const uint4*>(h1 + tb * 128);
  float a0 = 0.f, a1 = 0.f, a2 = 0.f, a3 = 0.f;
#pragma unroll
  for (int i = 0; i < 16; i++) {
    const uint4 u = hv[i];
    a0 = fdot2f(wl[4 * i + 0], u2h(u.x), a0);
    a1 = fdot2f(wl[4 * i + 1], u2h(u.y), a1);
    a2 = fdot2f(wl[4 * i + 2], u2h(u.z), a2);
    a3 = fdot2f(wl[4 * i + 3], u2h(u.w), a3);
  }
  out[tb] = (a0 + a1) + (a2 + a3) + blin[0];
}

extern "C" void kernel_launch(void* const* d_in, const int* in_sizes, int n_in,
                              void* d_out, int out_size, void* d_ws, size_t ws_size,
                              hipStream_t stream) {
  (void)in_sizes; (void)n_in; (void)out_size; (void)ws_size;

  const float* data = (const float*)d_in[0];
  const float* Wih0 = (const float*)d_in[1];
  const float* Whh0 = (const float*)d_in[2];
  const float* bih0 = (const float*)d_in[3];
  const float* bhh0 = (const float*)d_in[4];
  const float* Wih1 = (const float*)d_in[5];
  const float* Whh1 = (const float*)d_in[6];
  const float* bih1 = (const float*)d_in[7];
  const float* bhh1 = (const float*)d_in[8];
  const float* Wlin = (const float*)d_in[9];
  const float* blin = (const float*)d_in[10];

  // ws layout: xp 128 MiB | h0 32 MiB | h1 32 MiB
  unsigned char* ws = (unsigned char*)d_ws;
  unsigned short* xpb = (unsigned short*)ws;
  unsigned short* h0 = (unsigned short*)(ws + (size_t)128 * 1024 * 1024);
  unsigned short* h1 = (unsigned short*)(ws + (size_t)160 * 1024 * 1024);

  const int M = SEQ_T * BATCH;
  const int gemm_blocks = M / 64;

  xproj_gemm<64, true><<<dim3(gemm_blocks), dim3(512), 0, stream>>>(
      data, Wih0, bih0, bhh0, xpb);
  lstm_rec2<<<dim3(BATCH), dim3(512), 0, stream>>>(Whh0, xpb, h0);
  xproj_gemm<128, false><<<dim3(gemm_blocks), dim3(512), 0, stream>>>(
      h0, Wih1, bih1, bhh1, xpb);
  lstm_rec2<<<dim3(BATCH), dim3(512), 0, stream>>>(Whh1, xpb, h1);
  final_lin<<<dim3(M / 256), dim3(256), 0, stream>>>(h1, Wlin, blin, (float*)d_out);
}